// Round 6
// baseline (1235.578 us; speedup 1.0000x reference)
//
#include <hip/hip_runtime.h>
#include <hip/hip_bf16.h>
#include <stdint.h>

typedef __bf16 bf16;
typedef __attribute__((ext_vector_type(8))) __bf16 bf16x8;
typedef __attribute__((ext_vector_type(4))) float f32x4;
typedef __attribute__((ext_vector_type(8))) unsigned short u16x8;

#define LDS_U32 __attribute__((address_space(3))) uint32_t
#define GLB_U32 const __attribute__((address_space(1))) uint32_t
#define GLOAD16(g, l) __builtin_amdgcn_global_load_lds((GLB_U32*)(g), (LDS_U32*)(l), 16, 0, 0)

// Volatile inline-asm ds_read (no "memory" clobber): opaque to alias analysis,
// no conservative vmcnt drain. Ordering vs MFMA via lgkmcnt + sched_barrier(0).
#define DSR(dst, addr, OFFLIT) \
  asm volatile("ds_read_b128 %0, %1 offset:" OFFLIT : "=v"(dst) : "v"(addr))

#define WAIT_LGKM0() asm volatile("s_waitcnt lgkmcnt(0)")
#define WAIT_LGKM8() asm volatile("s_waitcnt lgkmcnt(8)")
#define WAIT_VM(n)   asm volatile("s_waitcnt vmcnt(" #n ")")

// ---------------- fused f32 -> bf16 convert (all 5 inputs, one launch) ----------------
__global__ __launch_bounds__(256) void cvt_all(const float* __restrict__ q,
                                               const float* __restrict__ wq,
                                               const float* __restrict__ wk,
                                               const float* __restrict__ wv,
                                               const float* __restrict__ wo,
                                               bf16* __restrict__ qb,
                                               bf16* __restrict__ W3,
                                               bf16* __restrict__ wob) {
  const int b = blockIdx.x;
  const float* src;
  bf16* dst;
  int within;
  if (b < 2048) { src = q; dst = qb; within = b; }
  else {
    const int seg = (b - 2048) >> 8;      // 0..3
    within = (b - 2048) & 255;
    if (seg == 0)      { src = wq; dst = W3; }
    else if (seg == 1) { src = wk; dst = W3 + 1048576; }
    else if (seg == 2) { src = wv; dst = W3 + 2097152; }
    else               { src = wo; dst = wob; }
  }
  const int off = within * 1024;
#pragma unroll
  for (int it = 0; it < 4; ++it) {
    const int j = off + it * 256 + threadIdx.x;
    float4 v = reinterpret_cast<const float4*>(src)[j];
    ushort4 o;
    o.x = __builtin_bit_cast(unsigned short, (bf16)v.x);
    o.y = __builtin_bit_cast(unsigned short, (bf16)v.y);
    o.z = __builtin_bit_cast(unsigned short, (bf16)v.z);
    o.w = __builtin_bit_cast(unsigned short, (bf16)v.w);
    reinterpret_cast<ushort4*>(dst)[j] = o;
  }
}

// ================= 256x256 8-phase GEMM, C = alpha * A @ B^T =================
// SINGLE-BUFFER 64 KiB LDS -> 2 blocks/CU (16 waves/CU TLP; 1.5-wave grids fit
// in one dispatch wave). Unit ring stages strictly after last-reader barriers:
//   A = [0,32KB): units 0..3 (64 rows x 64 k, 8KB). Per wave-half: units {0,1}
//     or {2,3}; phase ph reads region + ph*4096 -> units {0,2} read ph0-1,
//     units {1,3} read ph2-3. B = [32KB,64KB): all bF read in ph0 only.
//   ph1: stage B(T+1) x4 | ph2: stage A{0,2}(T+1) x2 | boundary: A{1,3}(T+1) x2
// Counted waits: vmcnt(4) end-ph1 (retires A{1,3}(T)); vmcnt(2) at boundary
// (retires B(T+1)+A{0,2}(T+1)). st_16x32 swizzle on both sides as before.
template <int EPI>
__global__ __launch_bounds__(512, 4) void g256(const bf16* __restrict__ A,
                                               const bf16* __restrict__ Bm,
                                               void* __restrict__ Cp,
                                               int K, float alpha,
                                               long sA, long sB, long sC, int ldc) {
  __shared__ bf16 smem_[32768];  // 64 KiB
  const long z = blockIdx.z;
  const int t = threadIdx.x;
  const int l = t & 63;
  const int w = t >> 6;
  const int wr = (w >> 2) * 128;  // wave row base within 256
  const int wc = (w & 3) * 64;    // wave col base within 256
  const int NT = K >> 6;

  const bf16* Ab = A + z * sA + (long)(blockIdx.y * 256) * K;
  const bf16* Bb = Bm + z * sB + (long)(blockIdx.x * 256) * K;

  // staging inverse map: thread t covers swizzled bytes [t*16, t*16+16) of one
  // 8KB 64-row unit; (r0,c0) = source row/col within the unit.
  uint32_t loc = (uint32_t)t * 16u;
  uint32_t g0 = loc ^ (((loc >> 9) & 1u) << 5);
  const int r0 = (int)(((g0 >> 10) >> 1) * 16 + ((g0 >> 6) & 15));  // 0..63
  const int c0 = (int)(((g0 >> 10) & 1) * 32 + ((g0 & 63) >> 1));   // 0..63

  // per-lane swizzled fragment read offset
  uint32_t lo_ = (uint32_t)((l & 15) * 64 + (l >> 4) * 16);
  const uint32_t lane_off = lo_ ^ (((lo_ >> 9) & 1u) << 5);
  const uint32_t aRegion = (uint32_t)(wr >> 7) * 16384u;
  const uint32_t bRegion = 32768u + (uint32_t)(wc >> 7) * 16384u;
  const int bR0 = (wc & 64) >> 4;  // B subtile row-group base (0 or 4)
  const uint32_t smem_base = (uint32_t)(size_t)&smem_[0];
  const uint32_t aAddr = smem_base + aRegion + lane_off;
  const uint32_t bAddr = smem_base + bRegion + (uint32_t)bR0 * 2048u + lane_off;

  auto STAGE1 = [&](const bf16* mat, int unit, int tile, uint32_t isB) {
    uint32_t dst = isB + (uint32_t)unit * 8192u + (uint32_t)t * 16u;
    const bf16* src = mat + (long)(unit * 64 + r0) * K + tile * 64 + c0;
    GLOAD16(src, smem_ + (dst >> 1));
  };

  f32x4 acc[8][4] = {};

  // ---- prologue: A(0) + B(0) fully staged
  STAGE1(Ab, 0, 0, 0u); STAGE1(Ab, 1, 0, 0u); STAGE1(Ab, 2, 0, 0u); STAGE1(Ab, 3, 0, 0u);
  STAGE1(Bb, 0, 0, 32768u); STAGE1(Bb, 1, 0, 32768u); STAGE1(Bb, 2, 0, 32768u); STAGE1(Bb, 3, 0, 32768u);
  __builtin_amdgcn_sched_barrier(0);
  WAIT_VM(0);
  __builtin_amdgcn_s_barrier();

#define MFMA16(ph)                                                                   \
  _Pragma("unroll") for (int mi = 0; mi < 2; ++mi)                                   \
  _Pragma("unroll") for (int n = 0; n < 4; ++n)                                      \
  _Pragma("unroll") for (int kk = 0; kk < 2; ++kk)                                   \
    acc[(ph) * 2 + mi][n] = __builtin_amdgcn_mfma_f32_16x16x32_bf16(                 \
        __builtin_bit_cast(bf16x8, aF[mi][kk]), __builtin_bit_cast(bf16x8, bF[n][kk]), \
        acc[(ph) * 2 + mi][n], 0, 0, 0);

  for (int T = 0; T < NT; ++T) {
    f32x4 bF[4][2];
    f32x4 aF[2][2];

    // ---------- phase 0: all bF (8) + aF quad0 (4); no staging ----------
    DSR(bF[0][0], bAddr, "0");    DSR(bF[0][1], bAddr, "1024");
    DSR(bF[1][0], bAddr, "2048"); DSR(bF[1][1], bAddr, "3072");
    DSR(bF[2][0], bAddr, "4096"); DSR(bF[2][1], bAddr, "5120");
    DSR(bF[3][0], bAddr, "6144"); DSR(bF[3][1], bAddr, "7168");
    DSR(aF[0][0], aAddr, "0");    DSR(aF[0][1], aAddr, "1024");
    DSR(aF[1][0], aAddr, "2048"); DSR(aF[1][1], aAddr, "3072");
    __builtin_amdgcn_sched_barrier(0);
    WAIT_LGKM8();
    __builtin_amdgcn_s_barrier();
    WAIT_LGKM0();
    __builtin_amdgcn_sched_barrier(0);
    __builtin_amdgcn_s_setprio(1);
    MFMA16(0)
    __builtin_amdgcn_s_setprio(0);
    __builtin_amdgcn_s_barrier();

    // ---------- phase 1: aF quad1; stage B(T+1); vmcnt(4) retires A{1,3}(T) ----------
    {
      const uint32_t aP = aAddr + 4096u;
      DSR(aF[0][0], aP, "0");    DSR(aF[0][1], aP, "1024");
      DSR(aF[1][0], aP, "2048"); DSR(aF[1][1], aP, "3072");
      if (T + 1 < NT) {
        STAGE1(Bb, 0, T + 1, 32768u); STAGE1(Bb, 1, T + 1, 32768u);
        STAGE1(Bb, 2, T + 1, 32768u); STAGE1(Bb, 3, T + 1, 32768u);
      }
      __builtin_amdgcn_sched_barrier(0);
      __builtin_amdgcn_s_barrier();
      WAIT_LGKM0();
      __builtin_amdgcn_sched_barrier(0);
      __builtin_amdgcn_s_setprio(1);
      MFMA16(1)
      __builtin_amdgcn_s_setprio(0);
      __builtin_amdgcn_sched_barrier(0);
      if (T + 1 < NT) { WAIT_VM(4); } else { WAIT_VM(0); }
      __builtin_amdgcn_sched_barrier(0);
      __builtin_amdgcn_s_barrier();
    }

    // ---------- phase 2: aF quad2 (units {1,3}); stage A{0,2}(T+1) ----------
    {
      const uint32_t aP = aAddr + 8192u;
      DSR(aF[0][0], aP, "0");    DSR(aF[0][1], aP, "1024");
      DSR(aF[1][0], aP, "2048"); DSR(aF[1][1], aP, "3072");
      if (T + 1 < NT) { STAGE1(Ab, 0, T + 1, 0u); STAGE1(Ab, 2, T + 1, 0u); }
      __builtin_amdgcn_sched_barrier(0);
      __builtin_amdgcn_s_barrier();
      WAIT_LGKM0();
      __builtin_amdgcn_sched_barrier(0);
      __builtin_amdgcn_s_setprio(1);
      MFMA16(2)
      __builtin_amdgcn_s_setprio(0);
      __builtin_amdgcn_s_barrier();
    }

    // ---------- phase 3: aF quad3; no staging ----------
    {
      const uint32_t aP = aAddr + 12288u;
      DSR(aF[0][0], aP, "0");    DSR(aF[0][1], aP, "1024");
      DSR(aF[1][0], aP, "2048"); DSR(aF[1][1], aP, "3072");
      __builtin_amdgcn_sched_barrier(0);
      __builtin_amdgcn_s_barrier();
      WAIT_LGKM0();
      __builtin_amdgcn_sched_barrier(0);
      __builtin_amdgcn_s_setprio(1);
      MFMA16(3)
      __builtin_amdgcn_s_setprio(0);
      __builtin_amdgcn_s_barrier();
    }

    // ---------- boundary: stage A{1,3}(T+1); vmcnt(2) retires B+A{0,2}(T+1) ----------
    if (T + 1 < NT) { STAGE1(Ab, 1, T + 1, 0u); STAGE1(Ab, 3, T + 1, 0u); }
    __builtin_amdgcn_sched_barrier(0);
    if (T + 1 < NT) { WAIT_VM(2); } else { WAIT_VM(0); }
    __builtin_amdgcn_sched_barrier(0);
    __builtin_amdgcn_s_barrier();
  }
#undef MFMA16

  // ---- epilogue: C/D layout col = lane&15, row = (lane>>4)*4 + i
  const int orow0 = blockIdx.y * 256 + wr + (l >> 4) * 4;
  const int ocol0 = blockIdx.x * 256 + wc + (l & 15);
#pragma unroll
  for (int m = 0; m < 8; ++m)
#pragma unroll
    for (int n = 0; n < 4; ++n)
#pragma unroll
      for (int i = 0; i < 4; ++i) {
        const long r = orow0 + m * 16 + i;
        const long c = ocol0 + n * 16;
        const float v = acc[m][n][i] * alpha;
        if constexpr (EPI == 0) {
          ((bf16*)Cp)[z * sC + r * ldc + c] = (bf16)v;
        } else if constexpr (EPI == 2) {
          ((float*)Cp)[r * ldc + c] = v;
        } else {
          // fused QKV epilogue: rows r = b*2048+s in [0,8192); cols c in [0,3072)
          bf16* Qb = (bf16*)Cp;
          bf16* Kb = Qb + 8388608;  // 8192*1024
          bf16* Vt = Kb + 8388608;
          if (c < 1024) Qb[r * 1024 + c] = (bf16)v;
          else if (c < 2048) Kb[r * 1024 + (c - 1024)] = (bf16)v;
          else Vt[(r >> 11) * 2097152 + (c - 2048) * 2048 + (r & 2047)] = (bf16)v;
        }
      }
}

// ---------------- row softmax, in place, rows of 2048 bf16 ----------------
__global__ __launch_bounds__(256) void softmax_rows(bf16* __restrict__ P) {
  const long row = blockIdx.x;
  bf16* p = P + row * 2048;
  const int t = threadIdx.x;
  const int lane = t & 63;
  const int wave = t >> 6;

  u16x8 raw = *reinterpret_cast<const u16x8*>(p + t * 8);
  float v[8];
#pragma unroll
  for (int j = 0; j < 8; ++j) {
    uint32_t bits = ((uint32_t)raw[j]) << 16;
    v[j] = __builtin_bit_cast(float, bits);
  }
  float m = v[0];
#pragma unroll
  for (int j = 1; j < 8; ++j) m = fmaxf(m, v[j]);
#pragma unroll
  for (int off = 32; off > 0; off >>= 1) m = fmaxf(m, __shfl_xor(m, off, 64));
  __shared__ float redm[4];
  __shared__ float reds[4];
  if (lane == 0) redm[wave] = m;
  __syncthreads();
  m = fmaxf(fmaxf(redm[0], redm[1]), fmaxf(redm[2], redm[3]));

  float s = 0.f;
#pragma unroll
  for (int j = 0; j < 8; ++j) {
    v[j] = __expf(v[j] - m);
    s += v[j];
  }
#pragma unroll
  for (int off = 32; off > 0; off >>= 1) s += __shfl_xor(s, off, 64);
  if (lane == 0) reds[wave] = s;
  __syncthreads();
  s = reds[0] + reds[1] + reds[2] + reds[3];
  const float inv = 1.f / s;

  u16x8 o;
#pragma unroll
  for (int j = 0; j < 8; ++j) o[j] = __builtin_bit_cast(unsigned short, (bf16)(v[j] * inv));
  *reinterpret_cast<u16x8*>(p + t * 8) = o;
}

// ---------------- launch ----------------
extern "C" void kernel_launch(void* const* d_in, const int* in_sizes, int n_in,
                              void* d_out, int out_size, void* d_ws, size_t ws_size,
                              hipStream_t stream) {
  const float* q = (const float*)d_in[0];
  const float* wq = (const float*)d_in[1];
  const float* wk = (const float*)d_in[2];
  const float* wv = (const float*)d_in[3];
  const float* wo = (const float*)d_in[4];
  float* out = (float*)d_out;

  constexpr int B = 4, S = 2048, D = 1024;
  constexpr long SD = (long)S * D;  // 2,097,152
  constexpr long SS = (long)S * S;  // 4,194,304
  constexpr long DD = (long)D * D;  // 1,048,576

  bf16* wsb = (bf16*)d_ws;
  bf16* qb = wsb;             // B*SD
  bf16* W3 = qb + B * SD;     // 3*DD  (wq;wk;wv stacked rows)
  bf16* wob = W3 + 3 * DD;    // DD
  bf16* Qb = wob + DD;        // B*SD
  bf16* Kb = Qb + B * SD;     // B*SD
  bf16* Vt = Kb + B * SD;     // B*SD, layout [B][D][S]
  bf16* P = Vt + B * SD;      // B*SS
  bf16* X = P + B * SS;       // B*SD, layout [B][D][S] == bugged buffer

  cvt_all<<<3072, 256, 0, stream>>>(q, wq, wk, wv, wo, qb, W3, wob);

  // fused QKV: [8192 x 1024] @ [3072 x 1024]^T -> Qb, Kb, Vt(transposed)
  g256<3><<<dim3(12, 32, 1), 512, 0, stream>>>(qb, W3, Qb, D, 1.f, 0, 0, 0, 0);
  // scores: P[b][i][j] = Q.K/8  (per batch 2048x2048, K=1024)
  g256<0><<<dim3(8, 8, B), 512, 0, stream>>>(Qb, Kb, P, D, 0.125f, SD, SD, SS, S);
  softmax_rows<<<B * S, 256, 0, stream>>>(P);
  // PV as Xt = Vt @ P^T: C[e][i] = sum_j Vt[e][j] P[i][j]  (M=1024, N=2048, K=2048)
  g256<0><<<dim3(8, 4, B), 512, 0, stream>>>(Vt, P, X, S, 1.f, SD, SS, SD, S);
  // out = Xflat[8192x1024] @ wo^T -> f32
  g256<2><<<dim3(4, 32, 1), 512, 0, stream>>>(X, wob, out, D, 1.f, 0, 0, 0, D);
}

// Round 7
// 250.046 us; speedup vs baseline: 4.9414x; 4.9414x over previous
//
#include <hip/hip_runtime.h>
#include <hip/hip_bf16.h>
#include <stdint.h>

typedef __bf16 bf16;
typedef __attribute__((ext_vector_type(8))) __bf16 bf16x8;
typedef __attribute__((ext_vector_type(4))) float f32x4;
typedef __attribute__((ext_vector_type(8))) unsigned short u16x8;

#define LDS_U32 __attribute__((address_space(3))) uint32_t
#define GLB_U32 const __attribute__((address_space(1))) uint32_t
#define GLOAD16(g, l) __builtin_amdgcn_global_load_lds((GLB_U32*)(g), (LDS_U32*)(l), 16, 0, 0)

// Volatile inline-asm ds_read (no "memory" clobber): opaque to alias analysis,
// no conservative vmcnt drain. Ordering vs MFMA via lgkmcnt + sched_barrier(0).
#define DSR(dst, addr, OFFLIT) \
  asm volatile("ds_read_b128 %0, %1 offset:" OFFLIT : "=v"(dst) : "v"(addr))

#define WAIT_LGKM0() asm volatile("s_waitcnt lgkmcnt(0)")
#define WAIT_LGKM8() asm volatile("s_waitcnt lgkmcnt(8)")
#define WAIT_VM(n)   asm volatile("s_waitcnt vmcnt(" #n ")")

// ---------------- fused f32 -> bf16 convert (all 5 inputs, one launch) ----------------
__global__ __launch_bounds__(256) void cvt_all(const float* __restrict__ q,
                                               const float* __restrict__ wq,
                                               const float* __restrict__ wk,
                                               const float* __restrict__ wv,
                                               const float* __restrict__ wo,
                                               bf16* __restrict__ qb,
                                               bf16* __restrict__ W3,
                                               bf16* __restrict__ wob) {
  const int b = blockIdx.x;
  const float* src;
  bf16* dst;
  int within;
  if (b < 2048) { src = q; dst = qb; within = b; }
  else {
    const int seg = (b - 2048) >> 8;      // 0..3
    within = (b - 2048) & 255;
    if (seg == 0)      { src = wq; dst = W3; }
    else if (seg == 1) { src = wk; dst = W3 + 1048576; }
    else if (seg == 2) { src = wv; dst = W3 + 2097152; }
    else               { src = wo; dst = wob; }
  }
  const int off = within * 1024;
#pragma unroll
  for (int it = 0; it < 4; ++it) {
    const int j = off + it * 256 + threadIdx.x;
    float4 v = reinterpret_cast<const float4*>(src)[j];
    ushort4 o;
    o.x = __builtin_bit_cast(unsigned short, (bf16)v.x);
    o.y = __builtin_bit_cast(unsigned short, (bf16)v.y);
    o.z = __builtin_bit_cast(unsigned short, (bf16)v.z);
    o.w = __builtin_bit_cast(unsigned short, (bf16)v.w);
    reinterpret_cast<ushort4*>(dst)[j] = o;
  }
}

// ================= 256x256 8-phase GEMM, C = alpha * A @ B^T =================
// SINGLE-BUFFER 64 KiB LDS. __launch_bounds__(512, 2): do NOT force 4 waves/EU
// — that caps VGPRs at 64 and spills acc[8][4] to scratch (round-6 disaster:
// 600MB scratch FETCH, MfmaUtil 0.35%). With (512,2) the allocator keeps
// ~104 VGPR + 128 acc AGPR (232/wave <= the 4-waves/SIMD budget of 512), and
// 2 blocks/CU co-residency comes from LDS fit (2 x 64KiB <= 160KiB) alone.
// Unit ring stages strictly after last-reader barriers:
//   A = [0,32KB): units 0..3 (64 rows x 64 k, 8KB). B = [32KB,64KB).
//   ph1: stage B(T+1) x4 | ph2: stage A{0,2}(T+1) x2 | boundary: A{1,3}(T+1) x2
// Counted waits: vmcnt(4) end-ph1 (retires A{1,3}(T)); vmcnt(2) at boundary
// (retires B(T+1)+A{0,2}(T+1)). st_16x32 swizzle on both sides as before.
template <int EPI>
__global__ __launch_bounds__(512, 2) void g256(const bf16* __restrict__ A,
                                               const bf16* __restrict__ Bm,
                                               void* __restrict__ Cp,
                                               int K, float alpha,
                                               long sA, long sB, long sC, int ldc) {
  __shared__ bf16 smem_[32768];  // 64 KiB
  const long z = blockIdx.z;
  const int t = threadIdx.x;
  const int l = t & 63;
  const int w = t >> 6;
  const int wr = (w >> 2) * 128;  // wave row base within 256
  const int wc = (w & 3) * 64;    // wave col base within 256
  const int NT = K >> 6;

  const bf16* Ab = A + z * sA + (long)(blockIdx.y * 256) * K;
  const bf16* Bb = Bm + z * sB + (long)(blockIdx.x * 256) * K;

  // staging inverse map: thread t covers swizzled bytes [t*16, t*16+16) of one
  // 8KB 64-row unit; (r0,c0) = source row/col within the unit.
  uint32_t loc = (uint32_t)t * 16u;
  uint32_t g0 = loc ^ (((loc >> 9) & 1u) << 5);
  const int r0 = (int)(((g0 >> 10) >> 1) * 16 + ((g0 >> 6) & 15));  // 0..63
  const int c0 = (int)(((g0 >> 10) & 1) * 32 + ((g0 & 63) >> 1));   // 0..63

  // per-lane swizzled fragment read offset
  uint32_t lo_ = (uint32_t)((l & 15) * 64 + (l >> 4) * 16);
  const uint32_t lane_off = lo_ ^ (((lo_ >> 9) & 1u) << 5);
  const uint32_t aRegion = (uint32_t)(wr >> 7) * 16384u;
  const uint32_t bRegion = 32768u + (uint32_t)(wc >> 7) * 16384u;
  const int bR0 = (wc & 64) >> 4;  // B subtile row-group base (0 or 4)
  const uint32_t smem_base = (uint32_t)(size_t)&smem_[0];
  const uint32_t aAddr = smem_base + aRegion + lane_off;
  const uint32_t bAddr = smem_base + bRegion + (uint32_t)bR0 * 2048u + lane_off;

  auto STAGE1 = [&](const bf16* mat, int unit, int tile, uint32_t isB) {
    uint32_t dst = isB + (uint32_t)unit * 8192u + (uint32_t)t * 16u;
    const bf16* src = mat + (long)(unit * 64 + r0) * K + tile * 64 + c0;
    GLOAD16(src, smem_ + (dst >> 1));
  };

  f32x4 acc[8][4] = {};

  // ---- prologue: A(0) + B(0) fully staged
  STAGE1(Ab, 0, 0, 0u); STAGE1(Ab, 1, 0, 0u); STAGE1(Ab, 2, 0, 0u); STAGE1(Ab, 3, 0, 0u);
  STAGE1(Bb, 0, 0, 32768u); STAGE1(Bb, 1, 0, 32768u); STAGE1(Bb, 2, 0, 32768u); STAGE1(Bb, 3, 0, 32768u);
  __builtin_amdgcn_sched_barrier(0);
  WAIT_VM(0);
  __builtin_amdgcn_s_barrier();

#define MFMA16(ph)                                                                   \
  _Pragma("unroll") for (int mi = 0; mi < 2; ++mi)                                   \
  _Pragma("unroll") for (int n = 0; n < 4; ++n)                                      \
  _Pragma("unroll") for (int kk = 0; kk < 2; ++kk)                                   \
    acc[(ph) * 2 + mi][n] = __builtin_amdgcn_mfma_f32_16x16x32_bf16(                 \
        __builtin_bit_cast(bf16x8, aF[mi][kk]), __builtin_bit_cast(bf16x8, bF[n][kk]), \
        acc[(ph) * 2 + mi][n], 0, 0, 0);

  for (int T = 0; T < NT; ++T) {
    f32x4 bF[4][2];
    f32x4 aF[2][2];

    // ---------- phase 0: all bF (8) + aF quad0 (4); no staging ----------
    DSR(bF[0][0], bAddr, "0");    DSR(bF[0][1], bAddr, "1024");
    DSR(bF[1][0], bAddr, "2048"); DSR(bF[1][1], bAddr, "3072");
    DSR(bF[2][0], bAddr, "4096"); DSR(bF[2][1], bAddr, "5120");
    DSR(bF[3][0], bAddr, "6144"); DSR(bF[3][1], bAddr, "7168");
    DSR(aF[0][0], aAddr, "0");    DSR(aF[0][1], aAddr, "1024");
    DSR(aF[1][0], aAddr, "2048"); DSR(aF[1][1], aAddr, "3072");
    __builtin_amdgcn_sched_barrier(0);
    WAIT_LGKM8();
    __builtin_amdgcn_s_barrier();
    WAIT_LGKM0();
    __builtin_amdgcn_sched_barrier(0);
    __builtin_amdgcn_s_setprio(1);
    MFMA16(0)
    __builtin_amdgcn_s_setprio(0);
    __builtin_amdgcn_s_barrier();

    // ---------- phase 1: aF quad1; stage B(T+1); vmcnt(4) retires A{1,3}(T) ----------
    {
      const uint32_t aP = aAddr + 4096u;
      DSR(aF[0][0], aP, "0");    DSR(aF[0][1], aP, "1024");
      DSR(aF[1][0], aP, "2048"); DSR(aF[1][1], aP, "3072");
      if (T + 1 < NT) {
        STAGE1(Bb, 0, T + 1, 32768u); STAGE1(Bb, 1, T + 1, 32768u);
        STAGE1(Bb, 2, T + 1, 32768u); STAGE1(Bb, 3, T + 1, 32768u);
      }
      __builtin_amdgcn_sched_barrier(0);
      __builtin_amdgcn_s_barrier();
      WAIT_LGKM0();
      __builtin_amdgcn_sched_barrier(0);
      __builtin_amdgcn_s_setprio(1);
      MFMA16(1)
      __builtin_amdgcn_s_setprio(0);
      __builtin_amdgcn_sched_barrier(0);
      if (T + 1 < NT) { WAIT_VM(4); } else { WAIT_VM(0); }
      __builtin_amdgcn_sched_barrier(0);
      __builtin_amdgcn_s_barrier();
    }

    // ---------- phase 2: aF quad2; stage A{0,2}(T+1) ----------
    {
      const uint32_t aP = aAddr + 8192u;
      DSR(aF[0][0], aP, "0");    DSR(aF[0][1], aP, "1024");
      DSR(aF[1][0], aP, "2048"); DSR(aF[1][1], aP, "3072");
      if (T + 1 < NT) { STAGE1(Ab, 0, T + 1, 0u); STAGE1(Ab, 2, T + 1, 0u); }
      __builtin_amdgcn_sched_barrier(0);
      __builtin_amdgcn_s_barrier();
      WAIT_LGKM0();
      __builtin_amdgcn_sched_barrier(0);
      __builtin_amdgcn_s_setprio(1);
      MFMA16(2)
      __builtin_amdgcn_s_setprio(0);
      __builtin_amdgcn_s_barrier();
    }

    // ---------- phase 3: aF quad3; no staging ----------
    {
      const uint32_t aP = aAddr + 12288u;
      DSR(aF[0][0], aP, "0");    DSR(aF[0][1], aP, "1024");
      DSR(aF[1][0], aP, "2048"); DSR(aF[1][1], aP, "3072");
      __builtin_amdgcn_sched_barrier(0);
      __builtin_amdgcn_s_barrier();
      WAIT_LGKM0();
      __builtin_amdgcn_sched_barrier(0);
      __builtin_amdgcn_s_setprio(1);
      MFMA16(3)
      __builtin_amdgcn_s_setprio(0);
      __builtin_amdgcn_s_barrier();
    }

    // ---------- boundary: stage A{1,3}(T+1); vmcnt(2) retires B+A{0,2}(T+1) ----------
    if (T + 1 < NT) { STAGE1(Ab, 1, T + 1, 0u); STAGE1(Ab, 3, T + 1, 0u); }
    __builtin_amdgcn_sched_barrier(0);
    if (T + 1 < NT) { WAIT_VM(2); } else { WAIT_VM(0); }
    __builtin_amdgcn_sched_barrier(0);
    __builtin_amdgcn_s_barrier();
  }
#undef MFMA16

  // ---- epilogue: C/D layout col = lane&15, row = (lane>>4)*4 + i
  const int orow0 = blockIdx.y * 256 + wr + (l >> 4) * 4;
  const int ocol0 = blockIdx.x * 256 + wc + (l & 15);
#pragma unroll
  for (int m = 0; m < 8; ++m)
#pragma unroll
    for (int n = 0; n < 4; ++n)
#pragma unroll
      for (int i = 0; i < 4; ++i) {
        const long r = orow0 + m * 16 + i;
        const long c = ocol0 + n * 16;
        const float v = acc[m][n][i] * alpha;
        if constexpr (EPI == 0) {
          ((bf16*)Cp)[z * sC + r * ldc + c] = (bf16)v;
        } else if constexpr (EPI == 2) {
          ((float*)Cp)[r * ldc + c] = v;
        } else {
          // fused QKV epilogue: rows r = b*2048+s in [0,8192); cols c in [0,3072)
          bf16* Qb = (bf16*)Cp;
          bf16* Kb = Qb + 8388608;  // 8192*1024
          bf16* Vt = Kb + 8388608;
          if (c < 1024) Qb[r * 1024 + c] = (bf16)v;
          else if (c < 2048) Kb[r * 1024 + (c - 1024)] = (bf16)v;
          else Vt[(r >> 11) * 2097152 + (c - 2048) * 2048 + (r & 2047)] = (bf16)v;
        }
      }
}

// ---------------- row softmax, in place, rows of 2048 bf16 ----------------
__global__ __launch_bounds__(256) void softmax_rows(bf16* __restrict__ P) {
  const long row = blockIdx.x;
  bf16* p = P + row * 2048;
  const int t = threadIdx.x;
  const int lane = t & 63;
  const int wave = t >> 6;

  u16x8 raw = *reinterpret_cast<const u16x8*>(p + t * 8);
  float v[8];
#pragma unroll
  for (int j = 0; j < 8; ++j) {
    uint32_t bits = ((uint32_t)raw[j]) << 16;
    v[j] = __builtin_bit_cast(float, bits);
  }
  float m = v[0];
#pragma unroll
  for (int j = 1; j < 8; ++j) m = fmaxf(m, v[j]);
#pragma unroll
  for (int off = 32; off > 0; off >>= 1) m = fmaxf(m, __shfl_xor(m, off, 64));
  __shared__ float redm[4];
  __shared__ float reds[4];
  if (lane == 0) redm[wave] = m;
  __syncthreads();
  m = fmaxf(fmaxf(redm[0], redm[1]), fmaxf(redm[2], redm[3]));

  float s = 0.f;
#pragma unroll
  for (int j = 0; j < 8; ++j) {
    v[j] = __expf(v[j] - m);
    s += v[j];
  }
#pragma unroll
  for (int off = 32; off > 0; off >>= 1) s += __shfl_xor(s, off, 64);
  if (lane == 0) reds[wave] = s;
  __syncthreads();
  s = reds[0] + reds[1] + reds[2] + reds[3];
  const float inv = 1.f / s;

  u16x8 o;
#pragma unroll
  for (int j = 0; j < 8; ++j) o[j] = __builtin_bit_cast(unsigned short, (bf16)(v[j] * inv));
  *reinterpret_cast<u16x8*>(p + t * 8) = o;
}

// ---------------- launch ----------------
extern "C" void kernel_launch(void* const* d_in, const int* in_sizes, int n_in,
                              void* d_out, int out_size, void* d_ws, size_t ws_size,
                              hipStream_t stream) {
  const float* q = (const float*)d_in[0];
  const float* wq = (const float*)d_in[1];
  const float* wk = (const float*)d_in[2];
  const float* wv = (const float*)d_in[3];
  const float* wo = (const float*)d_in[4];
  float* out = (float*)d_out;

  constexpr int B = 4, S = 2048, D = 1024;
  constexpr long SD = (long)S * D;  // 2,097,152
  constexpr long SS = (long)S * S;  // 4,194,304
  constexpr long DD = (long)D * D;  // 1,048,576

  bf16* wsb = (bf16*)d_ws;
  bf16* qb = wsb;             // B*SD
  bf16* W3 = qb + B * SD;     // 3*DD  (wq;wk;wv stacked rows)
  bf16* wob = W3 + 3 * DD;    // DD
  bf16* Qb = wob + DD;        // B*SD
  bf16* Kb = Qb + B * SD;     // B*SD
  bf16* Vt = Kb + B * SD;     // B*SD, layout [B][D][S]
  bf16* P = Vt + B * SD;      // B*SS
  bf16* X = P + B * SS;       // B*SD, layout [B][D][S] == bugged buffer

  cvt_all<<<3072, 256, 0, stream>>>(q, wq, wk, wv, wo, qb, W3, wob);

  // fused QKV: [8192 x 1024] @ [3072 x 1024]^T -> Qb, Kb, Vt(transposed)
  g256<3><<<dim3(12, 32, 1), 512, 0, stream>>>(qb, W3, Qb, D, 1.f, 0, 0, 0, 0);
  // scores: P[b][i][j] = Q.K/8  (per batch 2048x2048, K=1024)
  g256<0><<<dim3(8, 8, B), 512, 0, stream>>>(Qb, Kb, P, D, 0.125f, SD, SD, SS, S);
  softmax_rows<<<B * S, 256, 0, stream>>>(P);
  // PV as Xt = Vt @ P^T: C[e][i] = sum_j Vt[e][j] P[i][j]  (M=1024, N=2048, K=2048)
  g256<0><<<dim3(8, 4, B), 512, 0, stream>>>(Vt, P, X, S, 1.f, SD, SS, SD, S);
  // out = Xflat[8192x1024] @ wo^T -> f32
  g256<2><<<dim3(4, 32, 1), 512, 0, stream>>>(X, wob, out, D, 1.f, 0, 0, 0, D);
}